// Round 11
// baseline (300.969 us; speedup 1.0000x reference)
//
#include <hip/hip_runtime.h>

#define NB 1024
#define NS 1024
#define NT 32
#define L2E 1.44269504088896340736f
#define LN2 0.69314718055994530942f

typedef short        bfrag  __attribute__((ext_vector_type(8)));   // 8 bf16 (4 VGPR)
typedef float        cfrag  __attribute__((ext_vector_type(16)));  // 16 f32 acc
typedef __bf16       bf16x2 __attribute__((ext_vector_type(2)));
typedef float        f32x8  __attribute__((ext_vector_type(8)));
typedef float        f32x4  __attribute__((ext_vector_type(4)));
typedef float        f32x2  __attribute__((ext_vector_type(2)));
typedef unsigned int u32;
typedef unsigned int u32x4  __attribute__((ext_vector_type(4)));

__device__ __forceinline__ float fexp2(float x){ return __builtin_amdgcn_exp2f(x); }
__device__ __forceinline__ float flog2(float x){ return __builtin_amdgcn_logf(x); }

// RNE pack (prologue only)
__device__ __forceinline__ u32 pkbf_rne(float a, float b){
    f32x2 t; t.x = a; t.y = b;
    return __builtin_bit_cast(u32, __builtin_convertvector(t, bf16x2));
}
// truncation pack: single v_perm_b32. low16 = bf16_trunc(a), high16 = bf16_trunc(b).
__device__ __forceinline__ u32 pkbf_t(float a, float b){
    return __builtin_amdgcn_perm(__builtin_bit_cast(u32, b),
                                 __builtin_bit_cast(u32, a), 0x07060302u);
}
// wave-uniform power-of-2 exponent extract (clamped)
__device__ __forceinline__ int exref(float ref){
    u32 xb = __builtin_bit_cast(u32, ref);
    u32 xf = __builtin_amdgcn_readfirstlane(xb);
    int ex = (int)((xf >> 23) & 0xFFu) - 127;
    return ex < -120 ? -120 : (ex > 120 ? 120 : ex);
}

// row-space involution applied implicitly by packing C/D straight into B regs:
// swaps row blocks [4..7]<->[8..11] and [20..23]<->[24..27]. Pair-preserving.
__device__ __forceinline__ int rho(int k){
    int bb = (k >> 2) & 3;
    return (bb == 1 || bb == 2) ? (k ^ 12) : k;
}

union accu { cfrag c; f32x2 p[8]; };
union e8u  { f32x8 v; f32x2 p[4]; };

#define MFMA2(Au, Bu, C) __builtin_amdgcn_mfma_f32_32x32x16_bf16( \
    __builtin_bit_cast(bfrag, Au), __builtin_bit_cast(bfrag, Bu), (C), 0, 0, 0)

// ---------------- Phase 1: per-(batch,chunk) transfer matrix + gold ----------
// PAIRED loop: serial depth halved (64 rounds, was 127). The r6-r10 invariances
// (occupancy 34-56%, ILP x2, VALU +/-) pinned the bottleneck to the serial
// MFMA->pack->MFMA chain. Per pair (t even, t+1 odd):
//   FT = E*D_t*E*D_{t+1} = mfma2(frag(D_t*E^T), frag(E*D_{t+1}))   [off-path]
//   M  = pack(renorm?(mfma2(frag(FT), frag(M))))                    [on-path]
// frag(E*D_odd): lane-local col scale of f32 E copy (r10 machinery).
// frag(D_even*E^T): slot-row scale of constant frag(E^T); scale pairs
// d[rho(k)],d[rho(k)+1] via LDS broadcast b64 of committed exp2(e_even)
// (r6's cheap-broadcast mechanism, evens only). F-production for pair j+1 is
// issued between applies -> fills the apply chain's stall windows.
__global__ __launch_bounds__(128, 4) void crf_chunk(
    const float* __restrict__ logits, const float* __restrict__ trans,
    const int* __restrict__ tags, const int* __restrict__ lens,
    u32* __restrict__ wmat, float* __restrict__ woff,
    float* __restrict__ gpart, float* __restrict__ outz)
{
    __shared__ __align__(16) float dscall[2 * 256];   // per-wave: 2 bufs x 4 evens x 32

    const int tid = threadIdx.x;
    const int wv  = tid >> 6, lt = tid & 63;
    const int m   = lt & 31,  h  = lt >> 5;
    const int bc  = blockIdx.x * 2 + wv;
    const int b   = bc >> 3,  c  = bc & 7;
    float* dsc = dscall + wv * 256;

    if (blockIdx.x == 0 && tid == 0) *outz = 0.0f;    // replaces memset dispatch

    const float* base = logits + (size_t)b * NS * NT;
    const int    len  = lens[b];
    const int    tb   = b * NS;

    // f32 copies: frag(E) rows (for E*D_odd) and frag(E^T) rows (for D_even*E^T)
    e8u Et0, Et1, EB0, EB1;
    #pragma unroll
    for (int j = 0; j < 8; j++){
        Et0.v[j] = fexp2(L2E * trans[rho(     8*h + j)*NT + m]);
        Et1.v[j] = fexp2(L2E * trans[rho(16 + 8*h + j)*NT + m]);
        EB0.v[j] = fexp2(L2E * trans[m*NT + rho(     8*h + j)]);
        EB1.v[j] = fexp2(L2E * trans[m*NT + rho(16 + 8*h + j)]);
    }
    // even-d row offsets for the slot scale (loop-invariant, pair-aligned)
    const int ra0 = rho(8*h + 0), ra1 = rho(8*h + 2);
    const int ra2 = rho(8*h + 4), ra3 = rho(8*h + 6);
    const int rb0 = rho(16 + 8*h + 0), rb1 = rho(16 + 8*h + 2);
    const int rb2 = rho(16 + 8*h + 4), rb3 = rho(16 + 8*h + 6);

    // M = rho-permuted identity (packed bf16): slot k holds row rho(k)
    u32x4 M0, M1;
    #pragma unroll
    for (int d = 0; d < 4; d++){
        int k0 = 8*h + 2*d;      u32 v = 0;
        if (rho(k0)     == m) v |= 0x3F80u;
        if (rho(k0 + 1) == m) v |= 0x3F800000u;
        M0[d] = v;
        int k1 = 16 + 8*h + 2*d; v = 0;
        if (rho(k1)     == m) v |= 0x3F80u;
        if (rho(k1 + 1) == m) v |= 0x3F800000u;
        M1[d] = v;
    }

    cfrag zacc;
    #pragma unroll
    for (int q = 0; q < 16; q++) zacc[q] = 0.0f;

    int offi = 0;
    const int tbeg = c*128 + 1;

    float eA[8], eB[8];
    u32x4 Fa0, Fa1, Fb0, Fb1;

    auto issue = [&](float (&e)[8], int k){
        const int t0 = tbeg + k*8;
        #pragma unroll
        for (int i = 0; i < 8; i++){
            int t = t0 + i; t = t > (NS-1) ? (NS-1) : t;   // clamp c==7 tail
            e[i] = base[t*NT + m];
        }
    };
    // commit exp2 of the 4 EVEN-step emissions of group k (h==0 lanes, 32 rows)
    auto commitE = [&](float (&e)[8], int k){
        if (h == 0){
            float* sp = dsc + (k & 1)*128 + m;
            sp[0]  = fexp2(L2E * e[0]);
            sp[32] = fexp2(L2E * e[2]);
            sp[64] = fexp2(L2E * e[4]);
            sp[96] = fexp2(L2E * e[6]);
        }
    };

    // FT(pair i of group k) = E*D_even*E*D_odd -> frag, off critical path
    auto produceF = [&](float (&e)[8], int k, int i, u32x4 &F0, u32x4 &F1){
        const float* db = dsc + (k & 1)*128 + i*32;
        f32x2 ca0 = *(const f32x2*)(db + ra0);
        f32x2 ca1 = *(const f32x2*)(db + ra1);
        f32x2 ca2 = *(const f32x2*)(db + ra2);
        f32x2 ca3 = *(const f32x2*)(db + ra3);
        f32x2 cb0 = *(const f32x2*)(db + rb0);
        f32x2 cb1 = *(const f32x2*)(db + rb1);
        f32x2 cb2 = *(const f32x2*)(db + rb2);
        f32x2 cb3 = *(const f32x2*)(db + rb3);
        float s = fexp2(L2E * e[2*i + 1]);
        f32x2 s2; s2.x = s; s2.y = s;

        u32x4 Ae0, Ae1, Bo0, Bo1;
        f32x2 t;
        t = EB0.p[0]*ca0; Ae0[0] = pkbf_t(t.x, t.y);
        t = EB0.p[1]*ca1; Ae0[1] = pkbf_t(t.x, t.y);
        t = EB0.p[2]*ca2; Ae0[2] = pkbf_t(t.x, t.y);
        t = EB0.p[3]*ca3; Ae0[3] = pkbf_t(t.x, t.y);
        t = EB1.p[0]*cb0; Ae1[0] = pkbf_t(t.x, t.y);
        t = EB1.p[1]*cb1; Ae1[1] = pkbf_t(t.x, t.y);
        t = EB1.p[2]*cb2; Ae1[2] = pkbf_t(t.x, t.y);
        t = EB1.p[3]*cb3; Ae1[3] = pkbf_t(t.x, t.y);
        t = Et0.p[0]*s2;  Bo0[0] = pkbf_t(t.x, t.y);
        t = Et0.p[1]*s2;  Bo0[1] = pkbf_t(t.x, t.y);
        t = Et0.p[2]*s2;  Bo0[2] = pkbf_t(t.x, t.y);
        t = Et0.p[3]*s2;  Bo0[3] = pkbf_t(t.x, t.y);
        t = Et1.p[0]*s2;  Bo1[0] = pkbf_t(t.x, t.y);
        t = Et1.p[1]*s2;  Bo1[1] = pkbf_t(t.x, t.y);
        t = Et1.p[2]*s2;  Bo1[2] = pkbf_t(t.x, t.y);
        t = Et1.p[3]*s2;  Bo1[3] = pkbf_t(t.x, t.y);

        accu r;
        r.c = MFMA2(Ae0, Bo0, zacc);      // (D_e E^T)^T (E D_o) = E D_e E D_o = F^T
        r.c = MFMA2(Ae1, Bo1, r.c);
        F0[0] = pkbf_t(r.c[0],  r.c[1]);  F0[1] = pkbf_t(r.c[2],  r.c[3]);
        F0[2] = pkbf_t(r.c[4],  r.c[5]);  F0[3] = pkbf_t(r.c[6],  r.c[7]);
        F1[0] = pkbf_t(r.c[8],  r.c[9]);  F1[1] = pkbf_t(r.c[10], r.c[11]);
        F1[2] = pkbf_t(r.c[12], r.c[13]); F1[3] = pkbf_t(r.c[14], r.c[15]);
    };

    // M <- pack(renorm?(F*M)) : the serial critical path
    auto applyF = [&](u32x4 &F0, u32x4 &F1, bool rn){
        accu acc;
        acc.c = MFMA2(F0, M0, zacc);      // (F^T)^T M = F M
        acc.c = MFMA2(F1, M1, acc.c);
        if (rn){
            int ex = exref(fmaxf(acc.c[0], acc.c[8]));
            offi += ex;
            f32x2 s2; s2.x = s2.y = __builtin_bit_cast(float, (u32)(127 - ex) << 23);
            #pragma unroll
            for (int q = 0; q < 8; q++) acc.p[q] *= s2;
        }
        M0[0] = pkbf_t(acc.c[0],  acc.c[1]);  M0[1] = pkbf_t(acc.c[2],  acc.c[3]);
        M0[2] = pkbf_t(acc.c[4],  acc.c[5]);  M0[3] = pkbf_t(acc.c[6],  acc.c[7]);
        M1[0] = pkbf_t(acc.c[8],  acc.c[9]);  M1[1] = pkbf_t(acc.c[10], acc.c[11]);
        M1[2] = pkbf_t(acc.c[12], acc.c[13]); M1[3] = pkbf_t(acc.c[14], acc.c[15]);
    };

    // group body: on entry Fa = F(pair0 of group k); exits with Fa = F(pair0, k+1)
    auto grp = [&](float (&ec)[8], float (&en)[8], int k){
        produceF(ec, k, 1, Fb0, Fb1);  applyF(Fa0, Fa1, false);
        produceF(ec, k, 2, Fa0, Fa1);  applyF(Fb0, Fb1, false);
        produceF(ec, k, 3, Fb0, Fb1);  applyF(Fa0, Fa1, false);
        commitE(en, k + 1);
        produceF(en, k + 1, 0, Fa0, Fa1);
        applyF(Fb0, Fb1, true);        // 8-step-window renorm
    };

    issue(eA, 0); commitE(eA, 0);
    produceF(eA, 0, 0, Fa0, Fa1);
    #pragma unroll 1
    for (int k = 0; k < 14; k += 2){
        issue(eB, k + 1);
        grp(eA, eB, k);
        issue(eA, k + 2);
        grp(eB, eA, k + 1);
    }
    issue(eB, 15);
    grp(eA, eB, 14);                   // also commits g15 evens + produces F(15,0)

    if (c != 7){                       // group 15: 4 pairs (wave-uniform branch)
        produceF(eB, 15, 1, Fb0, Fb1); applyF(Fa0, Fa1, false);
        produceF(eB, 15, 2, Fa0, Fa1); applyF(Fb0, Fb1, false);
        produceF(eB, 15, 3, Fb0, Fb1); applyF(Fa0, Fa1, false);
        applyF(Fb0, Fb1, false);
    } else {                           // chunk 7: 3 pairs + single step (t=1023)
        produceF(eB, 15, 1, Fb0, Fb1); applyF(Fa0, Fa1, false);
        produceF(eB, 15, 2, Fa0, Fa1); applyF(Fb0, Fb1, false);
        applyF(Fa0, Fa1, false);
        float s = fexp2(L2E * eB[6]);
        f32x2 s2; s2.x = s; s2.y = s;
        u32x4 As0, As1; f32x2 t;
        t = Et0.p[0]*s2; As0[0] = pkbf_t(t.x, t.y);
        t = Et0.p[1]*s2; As0[1] = pkbf_t(t.x, t.y);
        t = Et0.p[2]*s2; As0[2] = pkbf_t(t.x, t.y);
        t = Et0.p[3]*s2; As0[3] = pkbf_t(t.x, t.y);
        t = Et1.p[0]*s2; As1[0] = pkbf_t(t.x, t.y);
        t = Et1.p[1]*s2; As1[1] = pkbf_t(t.x, t.y);
        t = Et1.p[2]*s2; As1[2] = pkbf_t(t.x, t.y);
        t = Et1.p[3]*s2; As1[3] = pkbf_t(t.x, t.y);
        accu acc;
        acc.c = MFMA2(As0, M0, zacc);  // (E D)^T M = D E^T M
        acc.c = MFMA2(As1, M1, acc.c);
        M0[0] = pkbf_t(acc.c[0],  acc.c[1]);  M0[1] = pkbf_t(acc.c[2],  acc.c[3]);
        M0[2] = pkbf_t(acc.c[4],  acc.c[5]);  M0[3] = pkbf_t(acc.c[6],  acc.c[7]);
        M1[0] = pkbf_t(acc.c[8],  acc.c[9]);  M1[1] = pkbf_t(acc.c[10], acc.c[11]);
        M1[2] = pkbf_t(acc.c[12], acc.c[13]); M1[3] = pkbf_t(acc.c[14], acc.c[15]);
    }

    // ---- store frag contiguously per lane: wmat[bc*512 + lt*8 + d] (2x dwordx4)
    {
        u32* wp = wmat + (size_t)bc * 512 + (size_t)lt * 8;
        *(u32x4*)(wp)     = M0;
        *(u32x4*)(wp + 4) = M1;
    }
    if (lt == 0) woff[bc] = (float)offi;

    // ---- gold for this chunk's 128 positions (t = tbeg..tbeg+127), 2/lane.
    {
        const int t1 = tbeg + 2*lt;
        const int t2 = t1 + 1;
        const int i2 = t2 > (NS-1) ? (NS-1) : t2;   // c==7,lt==63: t2==1024
        const int g0 = tags[tb + t1 - 1];
        const int g1 = tags[tb + t1];
        const int g2 = tags[tb + i2];
        float gg = 0.0f;
        if (t1 < len) gg += base[t1*NT + g1] + trans[g0*NT + g1];
        if (t2 < len) gg += base[t2*NT + g2] + trans[g1*NT + g2];
        #pragma unroll
        for (int d = 1; d < 64; d <<= 1) gg += __shfl_xor(gg, d, 64);
        if (lt == 0){
            if (c == 0) gg += base[tags[tb]];        // t=0 emission
            gpart[bc] = gg;                          // plain store, no atomic
        }
    }
}

// ---------------- Phase 2: per-batch MFMA matrix-chain combine ----------------
// UNCHANGED from round 6 (verified).
__global__ __launch_bounds__(256) void crf_combine(
    const float* __restrict__ logits,
    const u32* __restrict__ wmat, const float* __restrict__ woff,
    const float* __restrict__ gpart, float* __restrict__ out)
{
    const int tid = threadIdx.x;
    const int wv  = tid >> 6, lt = tid & 63;
    const int m   = lt & 31,  h  = lt >> 5;
    const int b   = blockIdx.x * 4 + wv;
    const float* base = logits + (size_t)b * NS * NT;

    uint4 mf[16];
    const u32* wb = wmat + (size_t)b * 8 * 512 + (size_t)lt * 8;
    #pragma unroll
    for (int j = 0; j < 8; j++){
        mf[2*j]     = *(const uint4*)(wb + j*512);
        mf[2*j + 1] = *(const uint4*)(wb + j*512 + 4);
    }

    float4 gp0 = ((const float4*)(gpart + b*8))[0];
    float4 gp1 = ((const float4*)(gpart + b*8))[1];
    const float gold = (gp0.x + gp0.y) + (gp0.z + gp0.w)
                     + (gp1.x + gp1.y) + (gp1.z + gp1.w);

    float voff = 0.0f;
    #pragma unroll
    for (int cc = 0; cc < 8; cc++) voff += woff[b*8 + cc];

    u32x4 S0, S1;
    #pragma unroll
    for (int d = 0; d < 4; d++){
        int k0 = 8*h + 2*d;      u32 v = 0;
        if (rho(k0)     == m) v |= 0x3F80u;
        if (rho(k0 + 1) == m) v |= 0x3F800000u;
        S0[d] = v;
        int k1 = 16 + 8*h + 2*d; v = 0;
        if (rho(k1)     == m) v |= 0x3F80u;
        if (rho(k1 + 1) == m) v |= 0x3F800000u;
        S1[d] = v;
    }

    cfrag zacc;
    #pragma unroll
    for (int q = 0; q < 16; q++) zacc[q] = 0.0f;

    #pragma unroll
    for (int j = 7; j >= 0; j--){
        accu acc;
        acc.c = MFMA2(mf[2*j],     S0, zacc);
        acc.c = MFMA2(mf[2*j + 1], S1, acc.c);

        float mx = acc.c[0];
        #pragma unroll
        for (int q = 1; q < 16; q++) mx = fmaxf(mx, acc.c[q]);
        #pragma unroll
        for (int d = 1; d < 64; d <<= 1) mx = fmaxf(mx, __shfl_xor(mx, d, 64));
        int ex = exref(mx);
        float sc = __builtin_bit_cast(float, (u32)(127 - ex) << 23);
        #pragma unroll
        for (int q = 0; q < 16; q++) acc.c[q] *= sc;
        voff += (float)ex;

        S0[0] = pkbf_t(acc.c[0],  acc.c[1]);  S0[1] = pkbf_t(acc.c[2],  acc.c[3]);
        S0[2] = pkbf_t(acc.c[4],  acc.c[5]);  S0[3] = pkbf_t(acc.c[6],  acc.c[7]);
        S1[0] = pkbf_t(acc.c[8],  acc.c[9]);  S1[1] = pkbf_t(acc.c[10], acc.c[11]);
        S1[2] = pkbf_t(acc.c[12], acc.c[13]); S1[3] = pkbf_t(acc.c[14], acc.c[15]);
    }

    u32x4 V0, V1;
    #pragma unroll
    for (int d = 0; d < 4; d++){
        int k0 = 8*h + 2*d;
        V0[d] = pkbf_rne(fexp2(L2E * base[rho(k0)]), fexp2(L2E * base[rho(k0+1)]));
        int k1 = 16 + 8*h + 2*d;
        V1[d] = pkbf_rne(fexp2(L2E * base[rho(k1)]), fexp2(L2E * base[rho(k1+1)]));
    }

    accu fin;
    fin.c = MFMA2(S0, V0, zacc);
    fin.c = MFMA2(S1, V1, fin.c);

    float s = 0.0f;
    #pragma unroll
    for (int q = 0; q < 16; q++) s += fin.c[q];
    s += __shfl_xor(s, 32, 64);

    if (lt == 0){
        float logz = LN2 * (voff + flog2(s));
        atomicAdd(out, (logz - gold) * (1.0f / (float)NB));
    }
}

extern "C" void kernel_launch(void* const* d_in, const int* in_sizes, int n_in,
                              void* d_out, int out_size, void* d_ws, size_t ws_size,
                              hipStream_t stream) {
    const float* logits = (const float*)d_in[0];
    const float* trans  = (const float*)d_in[1];
    const int*   tags   = (const int*)d_in[2];
    const int*   lens   = (const int*)d_in[3];

    u32*   wmat  = (u32*)d_ws;                                   // 16 MB
    float* woff  = (float*)((char*)d_ws + 16u*1024u*1024u);      // 32 KB
    float* gpart = woff + 8192;                                  // 32 KB

    crf_chunk  <<<4096, 128, 0, stream>>>(logits, trans, tags, lens,
                                          wmat, woff, gpart, (float*)d_out);
    crf_combine<<< 256, 256, 0, stream>>>(logits, wmat, woff, gpart,
                                          (float*)d_out);
}